// Round 2
// baseline (4835.514 us; speedup 1.0000x reference)
//
#include <hip/hip_runtime.h>
#include <hip/hip_bf16.h>

typedef __hip_bfloat16 bf16;
typedef unsigned int uint32;

#define THREADS 512

__device__ __forceinline__ float2 bf2x2(uint32 u) {
  return make_float2(__uint_as_float(u << 16), __uint_as_float(u & 0xffff0000u));
}

__device__ __forceinline__ uint32 packbf2(float x, float y) {
  union { __hip_bfloat162 b; uint32 u; } cv;
  cv.b = __float22bfloat162_rn(make_float2(x, y));
  return cv.u;
}

// One GAT layer. x in LDS: sX[64][512] bf16 (K valid cols) -> out into sX
// (bf16, stride 512) or, for LAST, fp32 into (float*)sX stride 256.
// Weights/attention vectors/bias are FP32 in global.
template <int K, int M, int C, bool LAST>
__device__ __forceinline__ void gat_layer(
    int t, const float* __restrict__ W, const float* __restrict__ a_s,
    const float* __restrict__ a_d, const float* __restrict__ bias,
    bf16* sX, bf16* sH, float* sLS, float* sLD) {
  constexpr int MG = M / 16;        // column groups of 16
  constexpr int NG = THREADS / MG;  // row groups
  constexpr int RPT = 64 / NG;      // rows per thread
  const int mg = t % MG;
  const int ng = t / MG;

  // ---- h = x @ W  (fp32 accumulate) ----
  float acc[RPT][16];
#pragma unroll
  for (int r = 0; r < RPT; ++r)
#pragma unroll
    for (int c = 0; c < 16; ++c) acc[r][c] = 0.f;

  const float* __restrict__ wcol = W + mg * 16;
  for (int f = 0; f < K; f += 2) {
    float2 xv[RPT];
#pragma unroll
    for (int r = 0; r < RPT; ++r)
      xv[r] = bf2x2(*(const uint32*)(sX + (ng + r * NG) * 512 + f));
#pragma unroll
    for (int ff = 0; ff < 2; ++ff) {
      const float4* wp = (const float4*)(wcol + (size_t)(f + ff) * M);
      float4 w0 = wp[0], w1 = wp[1], w2 = wp[2], w3 = wp[3];
      float wv[16] = {w0.x, w0.y, w0.z, w0.w, w1.x, w1.y, w1.z, w1.w,
                      w2.x, w2.y, w2.z, w2.w, w3.x, w3.y, w3.z, w3.w};
#pragma unroll
      for (int r = 0; r < RPT; ++r) {
        float xs1 = ff ? xv[r].y : xv[r].x;
#pragma unroll
        for (int c = 0; c < 16; ++c) acc[r][c] = fmaf(xs1, wv[c], acc[r][c]);
      }
    }
  }
#pragma unroll
  for (int r = 0; r < RPT; ++r) {
    int row = ng + r * NG;
#pragma unroll
    for (int c = 0; c < 16; c += 2)
      *(uint32*)(sH + row * 512 + mg * 16 + c) = packbf2(acc[r][c], acc[r][c + 1]);
  }
  __syncthreads();

  // ---- ls[n,h] = h.a_src, ld[n,h] = h.a_dst ----
  {
    const int n = t & 63, hd = t >> 6;
    const bf16* hrow = sH + n * 512 + hd * C;
    float ls = 0.f, ld = 0.f;
#pragma unroll
    for (int c = 0; c < C; c += 2) {
      float2 hv = bf2x2(*(const uint32*)(hrow + c));
      float2 av = *(const float2*)(a_s + hd * C + c);
      float2 dv = *(const float2*)(a_d + hd * C + c);
      ls = fmaf(hv.x, av.x, fmaf(hv.y, av.y, ls));
      ld = fmaf(hv.x, dv.x, fmaf(hv.y, dv.y, ld));
    }
    sLS[hd * 64 + n] = ls;
    sLD[hd * 64 + n] = ld;
  }
  __syncthreads();

  // ---- softmax over j of leaky_relu(ld[i]+ls[j]); out = attn @ h + b ----
  {
    const int i = t & 63, hd = t >> 6;  // wave <-> head: LDS h reads broadcast
    const float ldv = sLD[hd * 64 + i];
    const float* lsr = sLS + hd * 64;
    float mx = -1e30f;
#pragma unroll 8
    for (int j = 0; j < 64; ++j) {
      float l = ldv + lsr[j];
      l = (l > 0.f) ? l : 0.2f * l;
      mx = fmaxf(mx, l);
    }
    float ssum = 0.f;
#pragma unroll 8
    for (int j = 0; j < 64; ++j) {
      float l = ldv + lsr[j];
      l = (l > 0.f) ? l : 0.2f * l;
      ssum += __expf(l - mx);
    }
    const float rinv = 1.f / ssum;
    float av[C];
#pragma unroll
    for (int c = 0; c < C; ++c) av[c] = 0.f;
    for (int j = 0; j < 64; ++j) {
      float l = ldv + lsr[j];
      l = (l > 0.f) ? l : 0.2f * l;
      const float w = __expf(l - mx);
      const uint4* hp = (const uint4*)(sH + j * 512 + hd * C);
#pragma unroll
      for (int c8 = 0; c8 < C / 8; ++c8) {
        uint4 hv = hp[c8];
        float2 p0 = bf2x2(hv.x), p1 = bf2x2(hv.y);
        float2 p2 = bf2x2(hv.z), p3 = bf2x2(hv.w);
        av[c8 * 8 + 0] = fmaf(w, p0.x, av[c8 * 8 + 0]);
        av[c8 * 8 + 1] = fmaf(w, p0.y, av[c8 * 8 + 1]);
        av[c8 * 8 + 2] = fmaf(w, p1.x, av[c8 * 8 + 2]);
        av[c8 * 8 + 3] = fmaf(w, p1.y, av[c8 * 8 + 3]);
        av[c8 * 8 + 4] = fmaf(w, p2.x, av[c8 * 8 + 4]);
        av[c8 * 8 + 5] = fmaf(w, p2.y, av[c8 * 8 + 5]);
        av[c8 * 8 + 6] = fmaf(w, p3.x, av[c8 * 8 + 6]);
        av[c8 * 8 + 7] = fmaf(w, p3.y, av[c8 * 8 + 7]);
      }
    }
    if constexpr (LAST) {
      float* outp = (float*)sX;  // x dead after matmul; reuse as fp32 out
#pragma unroll
      for (int c = 0; c < C; c += 2) {
        float2 bv = *(const float2*)(bias + hd * C + c);
        outp[i * 256 + hd * C + c] = fmaf(av[c], rinv, bv.x);
        outp[i * 256 + hd * C + c + 1] = fmaf(av[c + 1], rinv, bv.y);
      }
    } else {
#pragma unroll
      for (int c = 0; c < C; c += 2) {
        float2 bv = *(const float2*)(bias + hd * C + c);
        *(uint32*)(sX + i * 512 + hd * C + c) =
            packbf2(fmaf(av[c], rinv, bv.x), fmaf(av[c + 1], rinv, bv.y));
      }
    }
  }
  __syncthreads();
}

__global__ __launch_bounds__(THREADS, 2) void gat3_kernel(
    const float* __restrict__ xs, const float* __restrict__ pe,
    const float* __restrict__ W1, const float* __restrict__ as1,
    const float* __restrict__ ad1, const float* __restrict__ b1,
    const float* __restrict__ W2, const float* __restrict__ as2,
    const float* __restrict__ ad2, const float* __restrict__ b2,
    const float* __restrict__ W3, const float* __restrict__ as3,
    const float* __restrict__ ad3, const float* __restrict__ b3,
    float* __restrict__ out) {
  extern __shared__ char smem[];
  bf16* sX = (bf16*)smem;                    // 64*512*2 = 65536 B
  bf16* sH = (bf16*)(smem + 64 * 1024);      // 65536 B
  float* sLS = (float*)(smem + 128 * 1024);  // 2048 B
  float* sLD = (float*)(smem + 130 * 1024);  // 2048 B

  const int t = threadIdx.x;
  const int blk = blockIdx.x;   // 0..2047 = bs*R
  const int bidx = blk >> 8;    // batch index (R=256)

  // build x0 = concat(xs[...,None], pos_enc broadcast) -> [64][32], stride 512
  for (int idx = t; idx < 64 * 32; idx += THREADS) {
    int n = idx >> 5, f = idx & 31;
    float v = (f == 0) ? xs[blk * 64 + n] : pe[(bidx * 64 + n) * 31 + (f - 1)];
    sX[n * 512 + f] = __float2bfloat16(v);
  }
  __syncthreads();

  gat_layer<32, 512, 64, false>(t, W1, as1, ad1, b1, sX, sH, sLS, sLD);
  gat_layer<512, 512, 64, false>(t, W2, as2, ad2, b2, sX, sH, sLS, sLD);
  gat_layer<512, 256, 32, true>(t, W3, as3, ad3, b3, sX, sH, sLS, sLD);

  // mean over the 64 nodes -> [256] per block
  const float* xf = (const float*)sX;
  if (t < 256) {
    float s = 0.f;
    for (int i = 0; i < 64; ++i) s += xf[i * 256 + t];
    out[blk * 256 + t] = s * 0.015625f;
  }
}

extern "C" void kernel_launch(void* const* d_in, const int* in_sizes, int n_in,
                              void* d_out, int out_size, void* d_ws, size_t ws_size,
                              hipStream_t stream) {
  const float* xs = (const float*)d_in[0];
  const float* pe = (const float*)d_in[1];
  const float* W1 = (const float*)d_in[2];
  const float* as1 = (const float*)d_in[3];
  const float* ad1 = (const float*)d_in[4];
  const float* b1 = (const float*)d_in[5];
  const float* W2 = (const float*)d_in[6];
  const float* as2 = (const float*)d_in[7];
  const float* ad2 = (const float*)d_in[8];
  const float* b2 = (const float*)d_in[9];
  const float* W3 = (const float*)d_in[10];
  const float* as3 = (const float*)d_in[11];
  const float* ad3 = (const float*)d_in[12];
  const float* b3 = (const float*)d_in[13];

  const size_t smem = 135168;  // 132 KiB dynamic LDS (<= 160 KiB/CU)
  (void)hipFuncSetAttribute((const void*)gat3_kernel,
                            hipFuncAttributeMaxDynamicSharedMemorySize,
                            (int)smem);
  gat3_kernel<<<dim3(2048), dim3(THREADS), smem, stream>>>(
      xs, pe, W1, as1, ad1, b1, W2, as2, ad2, b2, W3, as3, ad3, b3,
      (float*)d_out);
}

// Round 3
// 461.272 us; speedup vs baseline: 10.4830x; 10.4830x over previous
//
#include <hip/hip_runtime.h>
#include <hip/hip_bf16.h>

typedef __hip_bfloat16 bf16;
typedef unsigned int uint32;
typedef __attribute__((ext_vector_type(8))) short short8;
typedef __attribute__((ext_vector_type(4))) float float4v;

#define THREADS 512
#define LDX 520  // bf16 elems/row: 1040 B (16B-aligned, +4dw bank shift/row)

__device__ __forceinline__ float2 bf2x2(uint32 u) {
  return make_float2(__uint_as_float(u << 16), __uint_as_float(u & 0xffff0000u));
}
__device__ __forceinline__ bf16 f2b(float x) { return __float2bfloat16(x); }
__device__ __forceinline__ short f2bs(float x) {
  union { bf16 b; short s; } u;
  u.b = __float2bfloat16(x);
  return u.s;
}

// W (f32, K x M row-major) -> bf16 swizzled to MFMA-B-fragment order:
// dst[(k/32)*M*32 + n*32 + ((k/8)%4)*8 + (k%8)]. Output-contiguous mapping.
__global__ void convw_kernel(const float* __restrict__ W, bf16* __restrict__ dst,
                             int total, int Mlog) {
  int o = blockIdx.x * 256 + threadIdx.x;
  if (o >= total) return;
  int j = o & 7, kc = (o >> 3) & 3, rest = o >> 5;
  int M = 1 << Mlog;
  int n = rest & (M - 1), kb = rest >> Mlog;
  int k = kb * 32 + kc * 8 + j;
  dst[o] = __float2bfloat16(W[(size_t)k * M + n]);
}

// One GAT layer on MFMA. x: sX[64][LDX] bf16 (K valid cols). Output x' written
// back to sX (bf16) or, for LAST, fp32 stride-260 into (float*)sX.
// Wave w == head w; wave owns output cols [w*M/8, (w+1)*M/8) == its head.
template <int K, int M, int C, bool LAST>
__device__ __forceinline__ void gat_layer_mfma(
    int t, const bf16* __restrict__ Wswz, const float* __restrict__ a_s,
    const float* __restrict__ a_d, const float* __restrict__ bias,
    bf16* sX, bf16* sH, float* sLS, float* sLD, float* sMX, float* sRI) {
  constexpr int CT = M / 128;  // 16-col tiles per wave (4 or 2)
  constexpr int KS = K / 32;
  const int lane = t & 63;
  const int hu = __builtin_amdgcn_readfirstlane(t >> 6);  // wave/head id (SGPR)
  const int ln = lane & 15;
  const int kq = lane >> 4;
  const int colbase = hu * (M / 8);  // == hu*C

  // ---- phase 1: h = x @ W (MFMA) ----
  float4v acc[4][CT];
#pragma unroll
  for (int rt = 0; rt < 4; ++rt)
#pragma unroll
    for (int ct = 0; ct < CT; ++ct) acc[rt][ct] = (float4v)0.f;

  const bf16* aptr = sX + ln * LDX + kq * 8;
  const bf16* bptr = Wswz + (colbase + ln) * 32 + kq * 8;
#pragma unroll 2
  for (int ks = 0; ks < KS; ++ks) {
    short8 afr[4];
#pragma unroll
    for (int rt = 0; rt < 4; ++rt)
      afr[rt] = *(const short8*)(aptr + rt * 16 * LDX + ks * 32);
    short8 bfr[CT];
#pragma unroll
    for (int ct = 0; ct < CT; ++ct)
      bfr[ct] = *(const short8*)(bptr + (size_t)ks * (M * 32) + ct * 16 * 32);
#pragma unroll
    for (int rt = 0; rt < 4; ++rt)
#pragma unroll
      for (int ct = 0; ct < CT; ++ct)
        acc[rt][ct] = __builtin_amdgcn_mfma_f32_16x16x32_bf16(
            afr[rt], bfr[ct], acc[rt][ct], 0, 0, 0);
  }
  // write h (bf16, no bias). C/D layout: col=ln, row=kq*4+r.
#pragma unroll
  for (int rt = 0; rt < 4; ++rt)
#pragma unroll
    for (int ct = 0; ct < CT; ++ct)
#pragma unroll
      for (int r = 0; r < 4; ++r)
        sH[(rt * 16 + kq * 4 + r) * LDX + colbase + ct * 16 + ln] =
            f2b(acc[rt][ct][r]);

  // ---- phase 2: ls/ld (lane <-> node j; wave-local head) ----
  float lsv = 0.f, ldv = 0.f;
  {
    const bf16* hrow = sH + lane * LDX + colbase;
    const float* asp = a_s + hu * C;
    const float* adp = a_d + hu * C;
#pragma unroll
    for (int c = 0; c < C; c += 2) {
      float2 hv = bf2x2(*(const uint32*)(hrow + c));
      lsv = fmaf(hv.x, asp[c], fmaf(hv.y, asp[c + 1], lsv));
      ldv = fmaf(hv.x, adp[c], fmaf(hv.y, adp[c + 1], ldv));
    }
    sLS[hu * 64 + lane] = lsv;
    sLD[hu * 64 + lane] = ldv;
  }

  // ---- phase 3: softmax stats for row i == lane ----
  float mx = -1e30f;
#pragma unroll 8
  for (int j = 0; j < 64; ++j) {
    float tt = ldv + sLS[hu * 64 + j];
    float l = fmaxf(tt, 0.2f * tt);
    mx = fmaxf(mx, l);
  }
  float ssum = 0.f;
#pragma unroll 8
  for (int j = 0; j < 64; ++j) {
    float tt = ldv + sLS[hu * 64 + j];
    float l = fmaxf(tt, 0.2f * tt);
    ssum += __expf(l - mx);
  }
  float ri = 1.0f / ssum;
  sMX[hu * 64 + lane] = mx;
  sRI[hu * 64 + lane] = ri;

  // ---- phase 4: build P (softmax, rinv folded) directly in A-frag regs ----
  float lsr[2][8];
#pragma unroll
  for (int s = 0; s < 2; ++s) {
    float4 v0 = *(const float4*)(sLS + hu * 64 + s * 32 + kq * 8);
    float4 v1 = *(const float4*)(sLS + hu * 64 + s * 32 + kq * 8 + 4);
    lsr[s][0] = v0.x; lsr[s][1] = v0.y; lsr[s][2] = v0.z; lsr[s][3] = v0.w;
    lsr[s][4] = v1.x; lsr[s][5] = v1.y; lsr[s][6] = v1.z; lsr[s][7] = v1.w;
  }
  short8 pfr[4][2];
#pragma unroll
  for (int rt = 0; rt < 4; ++rt) {
    int i = rt * 16 + ln;
    float ldi = sLD[hu * 64 + i];
    float mxi = sMX[hu * 64 + i];
    float rii = sRI[hu * 64 + i];
#pragma unroll
    for (int s = 0; s < 2; ++s)
#pragma unroll
      for (int jj = 0; jj < 8; ++jj) {
        float tt = ldi + lsr[s][jj];
        float l = fmaxf(tt, 0.2f * tt);
        pfr[rt][s][jj] = f2bs(__expf(l - mxi) * rii);
      }
  }

  // ---- phase 5: O = P @ h (MFMA; B-frags strided u16 from row-major h) ----
  float4v oacc[4][CT];
#pragma unroll
  for (int rt = 0; rt < 4; ++rt)
#pragma unroll
    for (int ct = 0; ct < CT; ++ct) oacc[rt][ct] = (float4v)0.f;
#pragma unroll
  for (int s = 0; s < 2; ++s) {
    short8 hfr[CT];
#pragma unroll
    for (int ct = 0; ct < CT; ++ct)
#pragma unroll
      for (int jj = 0; jj < 8; ++jj)
        hfr[ct][jj] = *(const short*)(sH + (s * 32 + kq * 8 + jj) * LDX +
                                      colbase + ct * 16 + ln);
#pragma unroll
    for (int rt = 0; rt < 4; ++rt)
#pragma unroll
      for (int ct = 0; ct < CT; ++ct)
        oacc[rt][ct] = __builtin_amdgcn_mfma_f32_16x16x32_bf16(
            pfr[rt][s], hfr[ct], oacc[rt][ct], 0, 0, 0);
  }

  __syncthreads();  // all waves done reading sX (phase 1) before overwrite

  // ---- phase 6: x' = O + bias -> sX ----
#pragma unroll
  for (int ct = 0; ct < CT; ++ct) {
    float bv = bias[colbase + ct * 16 + ln];
#pragma unroll
    for (int rt = 0; rt < 4; ++rt)
#pragma unroll
      for (int r = 0; r < 4; ++r) {
        float val = oacc[rt][ct][r] + bv;
        int row = rt * 16 + kq * 4 + r;
        if constexpr (LAST)
          ((float*)sX)[row * 260 + colbase + ct * 16 + ln] = val;
        else
          sX[row * LDX + colbase + ct * 16 + ln] = f2b(val);
      }
  }
  __syncthreads();  // x' complete before next layer reads it
}

__global__ __launch_bounds__(THREADS, 2) void gat3_mfma(
    const float* __restrict__ xs, const float* __restrict__ pe,
    const bf16* __restrict__ W1s, const float* __restrict__ as1,
    const float* __restrict__ ad1, const float* __restrict__ b1,
    const bf16* __restrict__ W2s, const float* __restrict__ as2,
    const float* __restrict__ ad2, const float* __restrict__ b2,
    const bf16* __restrict__ W3s, const float* __restrict__ as3,
    const float* __restrict__ ad3, const float* __restrict__ b3,
    float* __restrict__ out) {
  extern __shared__ char smem[];
  bf16* sX = (bf16*)smem;                      // 64*520*2 = 66560 B
  bf16* sH = (bf16*)(smem + 66560);            // 66560 B
  float* sLS = (float*)(smem + 133120);        // 2048 B
  float* sLD = (float*)(smem + 135168);        // 2048 B
  float* sMX = (float*)(smem + 137216);        // 2048 B
  float* sRI = (float*)(smem + 139264);        // 2048 B  => total 141312

  const int t = threadIdx.x;
  const int blk = blockIdx.x;  // bs*R = 2048 graphs
  const int bidx = blk >> 8;   // batch index (R=256)

  // x0 = concat(xs, broadcast pos_enc) -> [64][32] bf16, stride LDX
  for (int idx = t; idx < 64 * 32; idx += THREADS) {
    int n = idx >> 5, f = idx & 31;
    float v = (f == 0) ? xs[blk * 64 + n] : pe[(bidx * 64 + n) * 31 + (f - 1)];
    sX[n * LDX + f] = __float2bfloat16(v);
  }
  __syncthreads();

  gat_layer_mfma<32, 512, 64, false>(t, W1s, as1, ad1, b1, sX, sH, sLS, sLD, sMX, sRI);
  gat_layer_mfma<512, 512, 64, false>(t, W2s, as2, ad2, b2, sX, sH, sLS, sLD, sMX, sRI);
  gat_layer_mfma<512, 256, 32, true>(t, W3s, as3, ad3, b3, sX, sH, sLS, sLD, sMX, sRI);

  // mean over 64 nodes -> [256]
  const float* xf = (const float*)sX;
  if (t < 256) {
    float s = 0.f;
#pragma unroll 8
    for (int i = 0; i < 64; ++i) s += xf[i * 260 + t];
    out[blk * 256 + t] = s * 0.015625f;
  }
}

extern "C" void kernel_launch(void* const* d_in, const int* in_sizes, int n_in,
                              void* d_out, int out_size, void* d_ws, size_t ws_size,
                              hipStream_t stream) {
  const float* xs = (const float*)d_in[0];
  const float* pe = (const float*)d_in[1];
  const float* W1 = (const float*)d_in[2];
  const float* as1 = (const float*)d_in[3];
  const float* ad1 = (const float*)d_in[4];
  const float* b1 = (const float*)d_in[5];
  const float* W2 = (const float*)d_in[6];
  const float* as2 = (const float*)d_in[7];
  const float* ad2 = (const float*)d_in[8];
  const float* b2 = (const float*)d_in[9];
  const float* W3 = (const float*)d_in[10];
  const float* as3 = (const float*)d_in[11];
  const float* ad3 = (const float*)d_in[12];
  const float* b3 = (const float*)d_in[13];

  // bf16-swizzled weights in workspace: 16384 + 262144 + 131072 elems
  bf16* W1s = (bf16*)d_ws;
  bf16* W2s = W1s + 16384;
  bf16* W3s = W2s + 262144;  // total 819200 B needed

  convw_kernel<<<dim3((16384 + 255) / 256), dim3(256), 0, stream>>>(W1, W1s, 16384, 9);
  convw_kernel<<<dim3((262144 + 255) / 256), dim3(256), 0, stream>>>(W2, W2s, 262144, 9);
  convw_kernel<<<dim3((131072 + 255) / 256), dim3(256), 0, stream>>>(W3, W3s, 131072, 8);

  const size_t smem = 141312;
  (void)hipFuncSetAttribute((const void*)gat3_mfma,
                            hipFuncAttributeMaxDynamicSharedMemorySize,
                            (int)smem);
  gat3_mfma<<<dim3(2048), dim3(THREADS), smem, stream>>>(
      xs, pe, W1s, as1, ad1, b1, W2s, as2, ad2, b2, W3s, as3, ad3, b3,
      (float*)d_out);
}

// Round 4
// 347.696 us; speedup vs baseline: 13.9073x; 1.3267x over previous
//
#include <hip/hip_runtime.h>
#include <hip/hip_bf16.h>

typedef __hip_bfloat16 bf16;
typedef unsigned int uint32;
typedef __attribute__((ext_vector_type(8))) short short8;
typedef __attribute__((ext_vector_type(4))) float float4v;

#define THREADS 512
#define LDX 520  // sX row stride in bf16 (260 dwords; /4=65 odd -> minimal b128 phases)
#define LDH 72   // hT col stride in bf16 (36 dwords; /4=9 odd -> minimal b128 phases)

__device__ __forceinline__ bf16 f2b(float x) { return __float2bfloat16(x); }
__device__ __forceinline__ short f2bs(float x) {
  union { bf16 b; short s; } u;
  u.b = __float2bfloat16(x);
  return u.s;
}
__device__ __forceinline__ uint32 packbf2(float x, float y) {
  union { __hip_bfloat162 b; uint32 u; } cv;
  cv.b = __float22bfloat162_rn(make_float2(x, y));
  return cv.u;
}

// All three W (f32, K x M row-major) -> bf16 in MFMA-B-fragment order:
// dst[(k/32)*M*32 + n*32 + ((k/8)%4)*8 + (k%8)], outputs concatenated.
__global__ void convw_all(const float* __restrict__ W1,
                          const float* __restrict__ W2,
                          const float* __restrict__ W3, bf16* __restrict__ dst) {
  int o = blockIdx.x * 256 + threadIdx.x;
  if (o >= 409600) return;
  const float* W;
  int Mlog, loc;
  if (o < 16384) { W = W1; Mlog = 9; loc = o; }
  else if (o < 278528) { W = W2; Mlog = 9; loc = o - 16384; }
  else { W = W3; Mlog = 8; loc = o - 278528; }
  int j = loc & 7, kc = (loc >> 3) & 3, rest = loc >> 5;
  int M = 1 << Mlog;
  int n = rest & (M - 1), kb = rest >> Mlog;
  int k = kb * 32 + kc * 8 + j;
  dst[o] = f2b(W[(size_t)k * M + n]);
}

// Extra 16-col B tiles: cols 0..7 = W@a_src per head, 8..15 = W@a_dst per head.
// Layout per layer: [ks][n(16)][kc(4)][j(8)]; layers concatenated (512|8192|8192).
__global__ void convE_all(
    const float* __restrict__ W1, const float* __restrict__ as1, const float* __restrict__ ad1,
    const float* __restrict__ W2, const float* __restrict__ as2, const float* __restrict__ ad2,
    const float* __restrict__ W3, const float* __restrict__ as3, const float* __restrict__ ad3,
    bf16* __restrict__ dstE) {
  int o = blockIdx.x * 256 + threadIdx.x;
  if (o >= 16896) return;
  const float *W, *as_, *ad_;
  int M, C, loc;
  if (o < 512) { loc = o; W = W1; as_ = as1; ad_ = ad1; M = 512; C = 64; }
  else if (o < 8704) { loc = o - 512; W = W2; as_ = as2; ad_ = ad2; M = 512; C = 64; }
  else { loc = o - 8704; W = W3; as_ = as3; ad_ = ad3; M = 256; C = 32; }
  int j = loc & 7, kc = (loc >> 3) & 3, n = (loc >> 5) & 15, ks = loc >> 9;
  int k = ks * 32 + kc * 8 + j;
  int head = n & 7;
  const float* a = (n < 8) ? as_ : ad_;
  float s = 0.f;
  for (int c = 0; c < C; ++c)
    s += W[(size_t)k * M + head * C + c] * a[head * C + c];
  dstE[o] = f2b(s);
}

// One GAT layer. Wave w == head w (wave owns output cols [w*M/8,(w+1)*M/8)).
// sX[64][LDX] bf16 in (K cols) -> out bf16 to sX, or LAST: fp32 stride-260.
template <int K, int M, int C, bool LAST>
__device__ __forceinline__ void gat_layer(
    int t, const bf16* __restrict__ Wswz, const bf16* __restrict__ WE,
    const float* __restrict__ bias, bf16* sX, bf16* sHT, float* sLS,
    float* sLD) {
  constexpr int CT = M / 128;  // 16-col tiles per wave
  constexpr int KS = K / 32;
  const int lane = t & 63;
  const int hu = __builtin_amdgcn_readfirstlane(t >> 6);  // wave/head id
  const int ln = lane & 15;
  const int kq = lane >> 4;
  const int colbase = hu * (M / 8);  // == hu*C

  // ---- phase 1: h = x@W (MFMA), plus ls/ld via extra [Was|Wad] tile ----
  float4v acc[4][CT], acce[4];
#pragma unroll
  for (int rt = 0; rt < 4; ++rt) {
    acce[rt] = (float4v)0.f;
#pragma unroll
    for (int ct = 0; ct < CT; ++ct) acc[rt][ct] = (float4v)0.f;
  }
  const bf16* aptr = sX + ln * LDX + kq * 8;
  const bf16* bptr = Wswz + (colbase + ln) * 32 + kq * 8;
  const bf16* eptr = WE + ln * 32 + kq * 8;
#pragma unroll 2
  for (int ks = 0; ks < KS; ++ks) {
    short8 afr[4];
#pragma unroll
    for (int rt = 0; rt < 4; ++rt)
      afr[rt] = *(const short8*)(aptr + rt * 16 * LDX + ks * 32);
    short8 efr = *(const short8*)(eptr + ks * 512);
    short8 bfr[CT];
#pragma unroll
    for (int ct = 0; ct < CT; ++ct)
      bfr[ct] = *(const short8*)(bptr + (size_t)ks * (M * 32) + ct * 16 * 32);
#pragma unroll
    for (int rt = 0; rt < 4; ++rt) {
      acce[rt] = __builtin_amdgcn_mfma_f32_16x16x32_bf16(afr[rt], efr, acce[rt], 0, 0, 0);
#pragma unroll
      for (int ct = 0; ct < CT; ++ct)
        acc[rt][ct] = __builtin_amdgcn_mfma_f32_16x16x32_bf16(
            afr[rt], bfr[ct], acc[rt][ct], 0, 0, 0);
    }
  }
  // h -> hT[col][row] (b64 writes; C/D layout col=ln, row=kq*4+r)
#pragma unroll
  for (int rt = 0; rt < 4; ++rt)
#pragma unroll
    for (int ct = 0; ct < CT; ++ct) {
      uint2 pv;
      pv.x = packbf2(acc[rt][ct][0], acc[rt][ct][1]);
      pv.y = packbf2(acc[rt][ct][2], acc[rt][ct][3]);
      *(uint2*)(sHT + (colbase + ct * 16 + ln) * LDH + rt * 16 + kq * 4) = pv;
    }
  // ls/ld: extra-tile C cols: col==hu -> ls, col==hu+8 -> ld (exec-masked)
#pragma unroll
  for (int rt = 0; rt < 4; ++rt)
#pragma unroll
    for (int r = 0; r < 4; ++r) {
      int row = rt * 16 + kq * 4 + r;
      if (ln == hu) sLS[hu * 64 + row] = acce[rt][r];
      if (ln == hu + 8) sLD[hu * 64 + row] = acce[rt][r];
    }

  __syncthreads();  // all waves done reading sX; sX writable in phase 6

  // ---- phase 3: per-head max of ls (leaky_relu monotone => exact row max) ----
  float maxls = sLS[hu * 64 + lane];
#pragma unroll
  for (int m = 1; m <= 32; m <<= 1) maxls = fmaxf(maxls, __shfl_xor(maxls, m, 64));

  float lsj[2][8];
#pragma unroll
  for (int s = 0; s < 2; ++s) {
    float4 v0 = *(const float4*)(sLS + hu * 64 + s * 32 + kq * 8);
    float4 v1 = *(const float4*)(sLS + hu * 64 + s * 32 + kq * 8 + 4);
    lsj[s][0] = v0.x; lsj[s][1] = v0.y; lsj[s][2] = v0.z; lsj[s][3] = v0.w;
    lsj[s][4] = v1.x; lsj[s][5] = v1.y; lsj[s][6] = v1.z; lsj[s][7] = v1.w;
  }

  // ---- phase 4: P rows in A-frag regs; row-sum via shfl; fold 1/sum ----
  short8 pfr[4][2];
#pragma unroll
  for (int rt = 0; rt < 4; ++rt) {
    const float ldi = sLD[hu * 64 + rt * 16 + ln];
    const float tm = ldi + maxls;
    const float mxi = fmaxf(tm, 0.2f * tm);
    float pe_[2][8];
    float rsum = 0.f;
#pragma unroll
    for (int s = 0; s < 2; ++s)
#pragma unroll
      for (int jj = 0; jj < 8; ++jj) {
        float tt = ldi + lsj[s][jj];
        float l = fmaxf(tt, 0.2f * tt);
        float e = __expf(l - mxi);
        pe_[s][jj] = e;
        rsum += e;
      }
    rsum += __shfl_xor(rsum, 16, 64);
    rsum += __shfl_xor(rsum, 32, 64);
    const float ri = 1.0f / rsum;
#pragma unroll
    for (int s = 0; s < 2; ++s)
#pragma unroll
      for (int jj = 0; jj < 8; ++jj) pfr[rt][s][jj] = f2bs(pe_[s][jj] * ri);
  }

  // ---- phase 5: O = P @ h (B-frags = contiguous b128 from hT) ----
  float4v oacc[4][CT];
#pragma unroll
  for (int rt = 0; rt < 4; ++rt)
#pragma unroll
    for (int ct = 0; ct < CT; ++ct) oacc[rt][ct] = (float4v)0.f;
#pragma unroll
  for (int s = 0; s < 2; ++s) {
    short8 hfr[CT];
#pragma unroll
    for (int ct = 0; ct < CT; ++ct)
      hfr[ct] = *(const short8*)(sHT + (colbase + ct * 16 + ln) * LDH + s * 32 + kq * 8);
#pragma unroll
    for (int rt = 0; rt < 4; ++rt)
#pragma unroll
      for (int ct = 0; ct < CT; ++ct)
        oacc[rt][ct] = __builtin_amdgcn_mfma_f32_16x16x32_bf16(
            pfr[rt][s], hfr[ct], oacc[rt][ct], 0, 0, 0);
  }

  // ---- phase 6: x' = O + bias ----
#pragma unroll
  for (int ct = 0; ct < CT; ++ct) {
    const float bv = bias[colbase + ct * 16 + ln];
#pragma unroll
    for (int rt = 0; rt < 4; ++rt)
#pragma unroll
      for (int r = 0; r < 4; ++r) {
        float val = oacc[rt][ct][r] + bv;
        int row = rt * 16 + kq * 4 + r;
        if constexpr (LAST)
          ((float*)sX)[row * 260 + colbase + ct * 16 + ln] = val;
        else
          sX[row * LDX + colbase + ct * 16 + ln] = f2b(val);
      }
  }
  __syncthreads();  // x' complete before next layer / mean
}

__global__ __launch_bounds__(THREADS, 2) void gat3_mfma(
    const float* __restrict__ xs, const float* __restrict__ pe,
    const bf16* __restrict__ W1s, const bf16* __restrict__ WE1,
    const float* __restrict__ b1, const bf16* __restrict__ W2s,
    const bf16* __restrict__ WE2, const float* __restrict__ b2,
    const bf16* __restrict__ W3s, const bf16* __restrict__ WE3,
    const float* __restrict__ b3, float* __restrict__ out) {
  extern __shared__ char smem[];
  bf16* sX = (bf16*)smem;                    // 64*520*2  = 66560 B
  bf16* sHT = (bf16*)(smem + 66560);         // 512*72*2  = 73728 B
  float* sLS = (float*)(smem + 140288);      // 2048 B
  float* sLD = (float*)(smem + 142336);      // 2048 B -> total 144384

  const int t = threadIdx.x;
  const int blk = blockIdx.x;  // bs*R = 2048 graphs
  const int bidx = blk >> 8;   // batch index (R=256)

  // x0 = concat(xs, broadcast pos_enc) -> [64][32] bf16, stride LDX
  for (int idx = t; idx < 64 * 32; idx += THREADS) {
    int n = idx >> 5, f = idx & 31;
    float v = (f == 0) ? xs[blk * 64 + n] : pe[(bidx * 64 + n) * 31 + (f - 1)];
    sX[n * LDX + f] = f2b(v);
  }
  __syncthreads();

  gat_layer<32, 512, 64, false>(t, W1s, WE1, b1, sX, sHT, sLS, sLD);
  gat_layer<512, 512, 64, false>(t, W2s, WE2, b2, sX, sHT, sLS, sLD);
  gat_layer<512, 256, 32, true>(t, W3s, WE3, b3, sX, sHT, sLS, sLD);

  // mean over 64 nodes -> [256]
  const float* xf = (const float*)sX;
  if (t < 256) {
    float s = 0.f;
#pragma unroll 8
    for (int i = 0; i < 64; ++i) s += xf[i * 260 + t];
    out[blk * 256 + t] = s * 0.015625f;
  }
}

extern "C" void kernel_launch(void* const* d_in, const int* in_sizes, int n_in,
                              void* d_out, int out_size, void* d_ws, size_t ws_size,
                              hipStream_t stream) {
  const float* xs = (const float*)d_in[0];
  const float* pe = (const float*)d_in[1];
  const float* W1 = (const float*)d_in[2];
  const float* as1 = (const float*)d_in[3];
  const float* ad1 = (const float*)d_in[4];
  const float* b1 = (const float*)d_in[5];
  const float* W2 = (const float*)d_in[6];
  const float* as2 = (const float*)d_in[7];
  const float* ad2 = (const float*)d_in[8];
  const float* b2 = (const float*)d_in[9];
  const float* W3 = (const float*)d_in[10];
  const float* as3 = (const float*)d_in[11];
  const float* ad3 = (const float*)d_in[12];
  const float* b3 = (const float*)d_in[13];

  bf16* Wall = (bf16*)d_ws;          // 409600 elems
  bf16* WEall = Wall + 409600;       // 16896 elems  (total 852992 B)
  bf16* W1s = Wall;
  bf16* W2s = Wall + 16384;
  bf16* W3s = Wall + 278528;
  bf16* WE1 = WEall;
  bf16* WE2 = WEall + 512;
  bf16* WE3 = WEall + 8704;

  convw_all<<<dim3(1600), dim3(256), 0, stream>>>(W1, W2, W3, Wall);
  convE_all<<<dim3(66), dim3(256), 0, stream>>>(W1, as1, ad1, W2, as2, ad2,
                                                W3, as3, ad3, WEall);

  const size_t smem = 144384;
  (void)hipFuncSetAttribute((const void*)gat3_mfma,
                            hipFuncAttributeMaxDynamicSharedMemorySize,
                            (int)smem);
  gat3_mfma<<<dim3(2048), dim3(THREADS), smem, stream>>>(
      xs, pe, W1s, WE1, b1, W2s, WE2, b2, W3s, WE3, b3, (float*)d_out);
}

// Round 5
// 288.513 us; speedup vs baseline: 16.7601x; 1.2051x over previous
//
#include <hip/hip_runtime.h>
#include <hip/hip_bf16.h>

typedef __hip_bfloat16 bf16;
typedef unsigned int uint32;
typedef __attribute__((ext_vector_type(8))) short short8;
typedef __attribute__((ext_vector_type(4))) float float4v;

#define THREADS 512
#define LDX 520  // sX row stride in bf16 (16B aligned; 260 dw -> +4-bank shift/row)

__device__ __forceinline__ bf16 f2b(float x) { return __float2bfloat16(x); }
__device__ __forceinline__ short f2bs(float x) {
  union { bf16 b; short s; } u;
  u.b = __float2bfloat16(x);
  return u.s;
}
__device__ __forceinline__ uint32 packbf2(float x, float y) {
  union { __hip_bfloat162 b; uint32 u; } cv;
  cv.b = __float22bfloat162_rn(make_float2(x, y));
  return cv.u;
}

// All three W (f32, K x M row-major) -> bf16 in MFMA-B-fragment order:
// dst[(k/32)*M*32 + n*32 + ((k/8)%4)*8 + (k%8)], outputs concatenated.
__global__ void convw_all(const float* __restrict__ W1,
                          const float* __restrict__ W2,
                          const float* __restrict__ W3, bf16* __restrict__ dst) {
  int o = blockIdx.x * 256 + threadIdx.x;
  if (o >= 409600) return;
  const float* W;
  int Mlog, loc;
  if (o < 16384) { W = W1; Mlog = 9; loc = o; }
  else if (o < 278528) { W = W2; Mlog = 9; loc = o - 16384; }
  else { W = W3; Mlog = 8; loc = o - 278528; }
  int j = loc & 7, kc = (loc >> 3) & 3, rest = loc >> 5;
  int M = 1 << Mlog;
  int n = rest & (M - 1), kb = rest >> Mlog;
  int k = kb * 32 + kc * 8 + j;
  dst[o] = f2b(W[(size_t)k * M + n]);
}

// Extra 16-col B tiles: cols 0..7 = W@a_src per head, 8..15 = W@a_dst per head.
// Layout per layer: [ks][n(16)][kc(4)][j(8)]; layers concatenated (512|8192|8192).
__global__ void convE_all(
    const float* __restrict__ W1, const float* __restrict__ as1, const float* __restrict__ ad1,
    const float* __restrict__ W2, const float* __restrict__ as2, const float* __restrict__ ad2,
    const float* __restrict__ W3, const float* __restrict__ as3, const float* __restrict__ ad3,
    bf16* __restrict__ dstE) {
  int o = blockIdx.x * 256 + threadIdx.x;
  if (o >= 16896) return;
  const float *W, *as_, *ad_;
  int M, C, loc;
  if (o < 512) { loc = o; W = W1; as_ = as1; ad_ = ad1; M = 512; C = 64; }
  else if (o < 8704) { loc = o - 512; W = W2; as_ = as2; ad_ = ad2; M = 512; C = 64; }
  else { loc = o - 8704; W = W3; as_ = as3; ad_ = ad3; M = 256; C = 32; }
  int j = loc & 7, kc = (loc >> 3) & 3, n = (loc >> 5) & 15, ks = loc >> 9;
  int k = ks * 32 + kc * 8 + j;
  int head = n & 7;
  const float* a = (n < 8) ? as_ : ad_;
  float s = 0.f;
  for (int c = 0; c < C; ++c)
    s += W[(size_t)k * M + head * C + c] * a[head * C + c];
  dstE[o] = f2b(s);
}

// One GAT layer. Wave w == head w (owns output cols [w*M/8,(w+1)*M/8)).
// h never touches LDS: C/D->B-frag permute done in-register via ds_bpermute.
template <int K, int M, int C, bool LAST>
__device__ __forceinline__ void gat_layer(
    int t, const bf16* __restrict__ Wswz, const bf16* __restrict__ WE,
    const float* __restrict__ bias, bf16* sX, float* sLS, float* sLD) {
  constexpr int CT = M / 128;  // 16-col tiles per wave
  constexpr int KS = K / 32;
  const int lane = t & 63;
  const int hu = __builtin_amdgcn_readfirstlane(t >> 6);  // wave/head id
  const int ln = lane & 15;
  const int kq = lane >> 4;
  const int colbase = hu * (M / 8);  // == hu*C

  // ---- phase 1: h = x@W (MFMA), plus ls/ld via extra [Was|Wad] tile ----
  float4v acc[4][CT], acce[4];
#pragma unroll
  for (int rt = 0; rt < 4; ++rt) {
    acce[rt] = (float4v)0.f;
#pragma unroll
    for (int ct = 0; ct < CT; ++ct) acc[rt][ct] = (float4v)0.f;
  }
  const bf16* aptr = sX + ln * LDX + kq * 8;
  const bf16* bptr = Wswz + (colbase + ln) * 32 + kq * 8;
  const bf16* eptr = WE + ln * 32 + kq * 8;
#pragma unroll 2
  for (int ks = 0; ks < KS; ++ks) {
    short8 afr[4];
#pragma unroll
    for (int rt = 0; rt < 4; ++rt)
      afr[rt] = *(const short8*)(aptr + rt * 16 * LDX + ks * 32);
    short8 efr = *(const short8*)(eptr + ks * 512);
    short8 bfr[CT];
#pragma unroll
    for (int ct = 0; ct < CT; ++ct)
      bfr[ct] = *(const short8*)(bptr + (size_t)ks * (M * 32) + ct * 16 * 32);
#pragma unroll
    for (int rt = 0; rt < 4; ++rt) {
      acce[rt] = __builtin_amdgcn_mfma_f32_16x16x32_bf16(afr[rt], efr, acce[rt], 0, 0, 0);
#pragma unroll
      for (int ct = 0; ct < CT; ++ct)
        acc[rt][ct] = __builtin_amdgcn_mfma_f32_16x16x32_bf16(
            afr[rt], bfr[ct], acc[rt][ct], 0, 0, 0);
    }
  }
  // ls/ld scatter (wave-private LDS regions; no barrier needed)
#pragma unroll
  for (int rt = 0; rt < 4; ++rt)
#pragma unroll
    for (int r = 0; r < 4; ++r) {
      int row = rt * 16 + kq * 4 + r;
      if (ln == hu) sLS[hu * 64 + row] = acce[rt][r];
      if (ln == hu + 8) sLD[hu * 64 + row] = acce[rt][r];
    }

  __syncthreads();  // all waves done reading sX -> phase 6 may overwrite

  // ---- softmax stats: per-head max of ls (leaky_relu monotone) ----
  float maxls = sLS[hu * 64 + lane];
#pragma unroll
  for (int m = 1; m <= 32; m <<= 1) maxls = fmaxf(maxls, __shfl_xor(maxls, m, 64));

  float lsj[2][8];
#pragma unroll
  for (int s = 0; s < 2; ++s) {
    float4 v0 = *(const float4*)(sLS + hu * 64 + s * 32 + kq * 8);
    float4 v1 = *(const float4*)(sLS + hu * 64 + s * 32 + kq * 8 + 4);
    lsj[s][0] = v0.x; lsj[s][1] = v0.y; lsj[s][2] = v0.z; lsj[s][3] = v0.w;
    lsj[s][4] = v1.x; lsj[s][5] = v1.y; lsj[s][6] = v1.z; lsj[s][7] = v1.w;
  }

  // ---- P rows in A-frag regs; row-sum via shfl; fold 1/sum ----
  short8 pfr[4][2];
#pragma unroll
  for (int rt = 0; rt < 4; ++rt) {
    const float ldi = sLD[hu * 64 + rt * 16 + ln];
    const float tm = ldi + maxls;
    const float mxi = fmaxf(tm, 0.2f * tm);
    float pe_[2][8];
    float rsum = 0.f;
#pragma unroll
    for (int s = 0; s < 2; ++s)
#pragma unroll
      for (int jj = 0; jj < 8; ++jj) {
        float tt = ldi + lsj[s][jj];
        float l = fmaxf(tt, 0.2f * tt);
        float e = __expf(l - mxi);
        pe_[s][jj] = e;
        rsum += e;
      }
    rsum += __shfl_xor(rsum, 16, 64);
    rsum += __shfl_xor(rsum, 32, 64);
    const float ri = 1.0f / rsum;
#pragma unroll
    for (int s = 0; s < 2; ++s)
#pragma unroll
      for (int jj = 0; jj < 8; ++jj) pfr[rt][s][jj] = f2bs(pe_[s][jj] * ri);
  }

  // ---- in-register transpose: acc (C/D layout) -> B-frags via ds_bpermute.
  // Row g bits b5..b0: held at lane kq=b3b2, reg(rt=b5b4, r=b1b0);
  // wanted at lane kq=b4b3, reg(s=b5, jj=b2b1b0). Pack r-pairs, 2 bperm + sel.
  const int kqhi = kq >> 1;
  const int addrA = 4 * (ln + 16 * ((kq & 1) << 1));  // jjp<2 src lane; +64 for jjp>=2
  short8 hfrA[CT][2];
#pragma unroll
  for (int ct = 0; ct < CT; ++ct) {
    uint32 Ppk[4][2];
#pragma unroll
    for (int rt = 0; rt < 4; ++rt) {
      Ppk[rt][0] = packbf2(acc[rt][ct][0], acc[rt][ct][1]);
      Ppk[rt][1] = packbf2(acc[rt][ct][2], acc[rt][ct][3]);
    }
#pragma unroll
    for (int s = 0; s < 2; ++s) {
      union { uint32 q[4]; short8 s8; } u;
#pragma unroll
      for (int jjp = 0; jjp < 4; ++jjp) {
        int addr = addrA + ((jjp >> 1) << 6);
        int lo = __builtin_amdgcn_ds_bpermute(addr, (int)Ppk[2 * s + 0][jjp & 1]);
        int hi = __builtin_amdgcn_ds_bpermute(addr, (int)Ppk[2 * s + 1][jjp & 1]);
        u.q[jjp] = kqhi ? (uint32)hi : (uint32)lo;
      }
      hfrA[ct][s] = u.s8;
    }
  }

  // ---- O = P @ h (all in regs) ----
  float4v oacc[4][CT];
#pragma unroll
  for (int rt = 0; rt < 4; ++rt)
#pragma unroll
    for (int ct = 0; ct < CT; ++ct) oacc[rt][ct] = (float4v)0.f;
#pragma unroll
  for (int s = 0; s < 2; ++s)
#pragma unroll
    for (int rt = 0; rt < 4; ++rt)
#pragma unroll
      for (int ct = 0; ct < CT; ++ct)
        oacc[rt][ct] = __builtin_amdgcn_mfma_f32_16x16x32_bf16(
            pfr[rt][s], hfrA[ct][s], oacc[rt][ct], 0, 0, 0);

  // ---- x' = O + bias -> sX ----
#pragma unroll
  for (int ct = 0; ct < CT; ++ct) {
    const float bv = bias[colbase + ct * 16 + ln];
#pragma unroll
    for (int rt = 0; rt < 4; ++rt)
#pragma unroll
      for (int r = 0; r < 4; ++r) {
        float val = oacc[rt][ct][r] + bv;
        int row = rt * 16 + kq * 4 + r;
        if constexpr (LAST)
          ((float*)sX)[row * 260 + colbase + ct * 16 + ln] = val;
        else
          sX[row * LDX + colbase + ct * 16 + ln] = f2b(val);
      }
  }
  __syncthreads();  // x' complete before next layer / mean
}

__global__ __launch_bounds__(THREADS, 4) void gat3_mfma(
    const float* __restrict__ xs, const float* __restrict__ pe,
    const bf16* __restrict__ W1s, const bf16* __restrict__ WE1,
    const float* __restrict__ b1, const bf16* __restrict__ W2s,
    const bf16* __restrict__ WE2, const float* __restrict__ b2,
    const bf16* __restrict__ W3s, const bf16* __restrict__ WE3,
    const float* __restrict__ b3, float* __restrict__ out) {
  extern __shared__ char smem[];
  bf16* sX = (bf16*)smem;                // 64*520*2 = 66560 B
  float* sLS = (float*)(smem + 66560);   // 2048 B
  float* sLD = (float*)(smem + 68608);   // 2048 B -> total 70656 (2 blocks/CU)

  const int t = threadIdx.x;
  const int blk = blockIdx.x;  // bs*R = 2048 graphs
  const int bidx = blk >> 8;   // batch index (R=256)

  // x0 = concat(xs, broadcast pos_enc) -> [64][32] bf16, stride LDX
  for (int idx = t; idx < 64 * 32; idx += THREADS) {
    int n = idx >> 5, f = idx & 31;
    float v = (f == 0) ? xs[blk * 64 + n] : pe[(bidx * 64 + n) * 31 + (f - 1)];
    sX[n * LDX + f] = f2b(v);
  }
  __syncthreads();

  gat_layer<32, 512, 64, false>(t, W1s, WE1, b1, sX, sLS, sLD);
  gat_layer<512, 512, 64, false>(t, W2s, WE2, b2, sX, sLS, sLD);
  gat_layer<512, 256, 32, true>(t, W3s, WE3, b3, sX, sLS, sLD);

  // mean over 64 nodes -> [256]
  const float* xf = (const float*)sX;
  if (t < 256) {
    float s = 0.f;
#pragma unroll 8
    for (int i = 0; i < 64; ++i) s += xf[i * 260 + t];
    out[blk * 256 + t] = s * 0.015625f;
  }
}

extern "C" void kernel_launch(void* const* d_in, const int* in_sizes, int n_in,
                              void* d_out, int out_size, void* d_ws, size_t ws_size,
                              hipStream_t stream) {
  const float* xs = (const float*)d_in[0];
  const float* pe = (const float*)d_in[1];
  const float* W1 = (const float*)d_in[2];
  const float* as1 = (const float*)d_in[3];
  const float* ad1 = (const float*)d_in[4];
  const float* b1 = (const float*)d_in[5];
  const float* W2 = (const float*)d_in[6];
  const float* as2 = (const float*)d_in[7];
  const float* ad2 = (const float*)d_in[8];
  const float* b2 = (const float*)d_in[9];
  const float* W3 = (const float*)d_in[10];
  const float* as3 = (const float*)d_in[11];
  const float* ad3 = (const float*)d_in[12];
  const float* b3 = (const float*)d_in[13];

  bf16* Wall = (bf16*)d_ws;          // 409600 elems
  bf16* WEall = Wall + 409600;       // 16896 elems (total 852992 B)
  bf16* W1s = Wall;
  bf16* W2s = Wall + 16384;
  bf16* W3s = Wall + 278528;
  bf16* WE1 = WEall;
  bf16* WE2 = WEall + 512;
  bf16* WE3 = WEall + 8704;

  convw_all<<<dim3(1600), dim3(256), 0, stream>>>(W1, W2, W3, Wall);
  convE_all<<<dim3(66), dim3(256), 0, stream>>>(W1, as1, ad1, W2, as2, ad2,
                                                W3, as3, ad3, WEall);

  const size_t smem = 70656;
  (void)hipFuncSetAttribute((const void*)gat3_mfma,
                            hipFuncAttributeMaxDynamicSharedMemorySize,
                            (int)smem);
  gat3_mfma<<<dim3(2048), dim3(THREADS), smem, stream>>>(
      xs, pe, W1s, WE1, b1, W2s, WE2, b2, W3s, WE3, b3, (float*)d_out);
}